// Round 9
// baseline (303.496 us; speedup 1.0000x reference)
//
#include <hip/hip_runtime.h>
#include <hip/hip_bf16.h>
#include <math.h>

#define B_   8192
#define F_   48
#define T_   512
#define L_   8
#define NBLK 256
#define THR  512
#define NW   8           // waves per block
#define RPB  32          // rows per block
#define HST  520         // H LDS row stride in shorts (1040B; 65 uint4)
#define ZS   52          // z LDS row stride in floats
#define LINE 32          // dwords per 128B line
#define NEVT 15          // E0 + (A_l,B_l) x 7 layers (value-slot indexing)
#define NGRP 16          // barrier tree: 16 groups x 16 blocks
#define GSZ  16
#define MAXV 6           // max values per event
// sync layout (dwords):
//   leafA[16 lines] rootA[1 line] leafB[16 lines] rootB[1 line] vals[NEVT][MAXV][NBLK]
#define ROOTA_OFF (NGRP * LINE)
#define LEAFB_OFF ((NGRP + 1) * LINE)
#define ROOTB_OFF ((2 * NGRP + 1) * LINE)
#define VALS_OFF  ((2 * NGRP + 2) * LINE)
#define SYNC_DW   (VALS_OFF + NEVT * MAXV * NBLK)

typedef unsigned short ushort_t;
typedef unsigned int   uint_t;
typedef __attribute__((ext_vector_type(8))) short short8;
typedef __attribute__((ext_vector_type(4))) float f32x4;

#define MFMA(a,b,c) __builtin_amdgcn_mfma_f32_16x16x32_bf16(a,b,c,0,0,0)

__device__ inline ushort_t f2bf(float x) {
    __hip_bfloat16 h = __float2bfloat16(x);
    return *reinterpret_cast<ushort_t*>(&h);
}
__device__ inline short8 negbf(short8 v) {
    short8 r;
    #pragma unroll
    for (int i = 0; i < 8; ++i) r[i] = v[i] ^ (short)0x8000;
    return r;
}
__device__ inline short8 pack8(float4 a, float4 b) {
    short8 r;
    r[0]=(short)f2bf(a.x); r[1]=(short)f2bf(a.y); r[2]=(short)f2bf(a.z); r[3]=(short)f2bf(a.w);
    r[4]=(short)f2bf(b.x); r[5]=(short)f2bf(b.y); r[6]=(short)f2bf(b.z); r[7]=(short)f2bf(b.w);
    return r;
}

__device__ inline float aload(const float* p) {
    return __hip_atomic_load(p, __ATOMIC_RELAXED, __HIP_MEMORY_SCOPE_AGENT);
}
__device__ inline void astore(float* p, float v) {
    __hip_atomic_store(p, v, __ATOMIC_RELAXED, __HIP_MEMORY_SCOPE_AGENT);
}

// ---------- prep: frag-linear bf16 layouts + zero barrier counters ----------
__global__ __launch_bounds__(256) void k_pre(
    const float* __restrict__ Ar, const float* __restrict__ Ai,
    const float* __restrict__ Dr, const float* __restrict__ Di,
    ushort_t* __restrict__ Afr, ushort_t* __restrict__ Afi,
    ushort_t* __restrict__ Atr, ushort_t* __restrict__ Ati,
    ushort_t* __restrict__ Dfr, ushort_t* __restrict__ Dfi,
    uint_t* __restrict__ syncbuf)
{
    const int gt = blockIdx.x * 256 + threadIdx.x;
    const int gs = gridDim.x * 256;
    if (gt < VALS_OFF) syncbuf[gt] = 0u;  // dense vals need no zeroing (stores)
    for (int idx = gt; idx < L_ * 32768; idx += gs) {
        int j = idx & 7, rest = idx >> 3;
        int mm = rest & 15; rest >>= 4;
        int qq = rest & 3;  rest >>= 2;
        int k2 = rest & 1;  rest >>= 1;
        int tile = rest & 31;
        int l = rest >> 5;
        int t = tile * 16 + mm, k = k2 * 32 + qq * 8 + j;
        float vr = 0.f, vi = 0.f;
        if (k < 48) { int g = l * 24576 + t * 48 + k; vr = Ar[g]; vi = Ai[g]; }
        Afr[idx] = f2bf(vr); Afi[idx] = f2bf(vi);
    }
    for (int idx = gt; idx < L_ * 24576; idx += gs) {
        int j = idx & 7, rest = idx >> 3;
        int mm = rest & 15; rest >>= 4;
        int qq = rest & 3;  rest >>= 2;
        int ks = rest & 15; rest >>= 4;
        int ft = rest % 3;
        int l = rest / 3;
        int f = ft * 16 + mm, k = ks * 32 + qq * 8 + j;
        int g = l * 24576 + k * 48 + f;
        Atr[idx] = f2bf(Ar[g]); Ati[idx] = f2bf(Ai[g]);
    }
    for (int idx = gt; idx < 24576; idx += gs) {
        int j = idx & 7, rest = idx >> 3;
        int mm = rest & 15; rest >>= 4;
        int qq = rest & 3;  rest >>= 2;
        int ks = rest & 15;
        int ft = rest >> 4;
        int f = ft * 16 + mm, k = ks * 32 + qq * 8 + j;
        Dfr[idx] = f2bf(Dr[k * 48 + f]); Dfi[idx] = f2bf(Di[k * 48 + f]);
    }
}

// ---------- persistent kernel (regular launch; 256 blocks = 1/CU by LDS) ----
// TWO independent cumulative tree-counter chains (16 leaves x 16 blocks + root):
//   B-chain: E0 (sigma_0, idx 0) then B_l {S1..S6} (idx l+1), consumed for lambda.
//   A-chain: A_l {cr,ci} (idx l), consumed for b_l.
// Chain-safety: a block reaches chain event k+1 only after an event that
// globally completes AFTER every block's k-bump of that chain (via consume
// dependencies), so cumulative leaf thresholds fire exactly at completion.
// Transport discipline (the measured-best R1 recipe): per-block slot STORES,
// release RMW arrivals, s_sleep(2)-every-iteration root polling, parallel
// dense gather on consume.
__global__ __launch_bounds__(THR, 2) void k_lamp(
    const float* __restrict__ u,
    const ushort_t* __restrict__ Afr, const ushort_t* __restrict__ Afi,
    const ushort_t* __restrict__ Atr, const ushort_t* __restrict__ Ati,
    const ushort_t* __restrict__ Dfr, const ushort_t* __restrict__ Dfi,
    const float* __restrict__ th,
    uint_t* syncbuf,
    float* __restrict__ out)
{
    extern __shared__ char dyn[];
    float*    pR   = (float*)dyn;                  // [8][3][16][17] 26112 B
    float*    pI   = pR + 8 * 3 * 16 * 17;         // 26112 B
    float*    zreL = pI + 8 * 3 * 16 * 17;         // 6656 B
    float*    zimL = zreL + RPB * ZS;              // 6656 B
    float*    red  = zimL + RPB * ZS;              // 512 B (128 floats)
    ushort_t* HreL = (ushort_t*)(red + 128);       // 33280 B
    ushort_t* HimL = HreL + RPB * HST;             // 33280 B  => 132608 B

    uint_t* leafA = syncbuf;
    uint_t* rootA = syncbuf + ROOTA_OFF;
    uint_t* leafB = syncbuf + LEAFB_OFF;
    uint_t* rootB = syncbuf + ROOTB_OFF;
    float*  vals  = (float*)syncbuf + VALS_OFF;    // [NEVT][MAXV][NBLK]

    const int tid = threadIdx.x, blk = blockIdx.x;
    const int grp = blk >> 4;                      // 16 blocks per leaf group
    const int row0 = blk * RPB;
    const int wave = tid >> 6, lane = tid & 63;
    const int quad = lane >> 4, m = lane & 15;
    const int rows16 = (wave >> 2) * 16;           // fwd: which 16-row tile
    const int rt = wave >> 2, kq = wave & 3;       // bwd: row-tile / K-quarter
    const float2* u2 = (const float2*)u;

    // tid0: arrive at tree (release leaf RMW; crossing block acquires leaf,
    // release-bumps root). Fire-and-forget; no waiting here.
    auto arrive = [&](uint_t* leaf, uint_t* root, int k) {
        uint_t* lf = leaf + (size_t)grp * LINE;
        uint_t old = __hip_atomic_fetch_add(lf, 1u, __ATOMIC_RELEASE,
                                            __HIP_MEMORY_SCOPE_AGENT);
        if (old == (uint_t)(GSZ * (k + 1)) - 1u) {
            (void)__hip_atomic_load(lf, __ATOMIC_ACQUIRE, __HIP_MEMORY_SCOPE_AGENT);
            (void)__hip_atomic_fetch_add(root, 1u, __ATOMIC_RELEASE,
                                         __HIP_MEMORY_SCOPE_AGENT);
        }
    };
    auto publishv = [&](uint_t* leaf, uint_t* root, int k, int evidx,
                        const float* v, int nv) {
        float* base = vals + (size_t)evidx * MAXV * NBLK;
        for (int j = 0; j < nv; ++j) astore(base + j * NBLK + blk, v[j]);
        arrive(leaf, root, k);
    };
    // tid0 polls root (sleep(2) EVERY iteration — the 176-recipe cadence);
    // waves 0..nv-1 gather dense 256-float arrays in parallel.
    auto consume = [&](uint_t* root, int k, int evidx, int nv) {
        if (tid == 0) {
            uint_t tgt = (uint_t)NGRP * (uint_t)(k + 1);
            while (__hip_atomic_load(root, __ATOMIC_RELAXED,
                                     __HIP_MEMORY_SCOPE_AGENT) < tgt)
                __builtin_amdgcn_s_sleep(2);
            (void)__hip_atomic_load(root, __ATOMIC_ACQUIRE,
                                    __HIP_MEMORY_SCOPE_AGENT);
        }
        __syncthreads();
        if (wave < nv) {
            const float* base = vals + (size_t)evidx * MAXV * NBLK + (size_t)wave * NBLK;
            float s = 0.f;
            #pragma unroll
            for (int g = 0; g < NBLK / 64; ++g) s += aload(base + g * 64 + lane);
            #pragma unroll
            for (int o = 32; o > 0; o >>= 1) s += __shfl_xor(s, o, 64);
            if (lane == 0) red[wave] = s;
        }
        __syncthreads();
    };

    // persistent H fragments (f32)
    f32x4 hR[8], hI[8];
    #pragma unroll
    for (int ct = 0; ct < 8; ++ct) { hR[ct] = (f32x4){0,0,0,0}; hI[ct] = (f32x4){0,0,0,0}; }

    // prologue: u -> regs + z LDS; ||u||^2 partial -> B-chain event 0
    float uRe[3], uIm[3];
    float acc = 0.f;
    #pragma unroll
    for (int k3 = 0; k3 < 3; ++k3) {
        int j = tid + k3 * THR;
        int r = j / 48, c = j - r * 48;
        float2 v = u2[(row0 + r) * 48 + c];
        uRe[k3] = v.x; uIm[k3] = v.y;
        zreL[r * ZS + c] = v.x; zimL[r * ZS + c] = v.y;
        acc += v.x * v.x + v.y * v.y;
    }
    #pragma unroll
    for (int o = 32; o > 0; o >>= 1) acc += __shfl_xor(acc, o, 64);
    __syncthreads();                         // publishes z LDS
    if (lane == 0) red[16 + wave] = acc;
    __syncthreads();
    if (tid == 0) {
        float t = 0.f;
        #pragma unroll
        for (int w = 0; w < NW; ++w) t += red[16 + w];
        publishv(leafB, rootB, 0, 0, &t, 1);
    }

    float lam = 0.f, bre = 0.f, bim = 0.f;
    for (int l = 0; l < L_; ++l) {
        const float th1 = th[l * 3 + 1];

        // z A-frags from LDS fp32 (K=48 padded to 64)
        const float* zpr = zreL + (rows16 + m) * ZS;
        const float* zpi = zimL + (rows16 + m) * ZS;
        short8 zr0 = pack8(*(const float4*)(zpr + quad * 8), *(const float4*)(zpr + quad * 8 + 4));
        short8 zi0 = pack8(*(const float4*)(zpi + quad * 8), *(const float4*)(zpi + quad * 8 + 4));
        short8 zr1 = {0,0,0,0,0,0,0,0}, zi1 = {0,0,0,0,0,0,0,0};
        if (quad < 2) {
            zr1 = pack8(*(const float4*)(zpr + 32 + quad * 8), *(const float4*)(zpr + 36 + quad * 8));
            zi1 = pack8(*(const float4*)(zpi + 32 + quad * 8), *(const float4*)(zpi + 36 + quad * 8));
        }
        short8 zin0 = negbf(zi0), zin1 = negbf(zi1);

        // forward GEMM accumulating straight onto H_old
        const ushort_t* Aflr = Afr + (size_t)l * 32768;
        const ushort_t* Afli = Afi + (size_t)l * 32768;
        #pragma unroll
        for (int ct = 0; ct < 8; ++ct) {
            const int tile = (wave & 3) * 8 + ct;
            const ushort_t* rp = Aflr + (size_t)(tile * 2) * 512 + lane * 8;
            const ushort_t* ip = Afli + (size_t)(tile * 2) * 512 + lane * 8;
            short8 ar0 = *(const short8*)rp;
            short8 ar1 = *(const short8*)(rp + 512);
            short8 ai0 = *(const short8*)ip;
            short8 ai1 = *(const short8*)(ip + 512);
            hR[ct] = MFMA(zr0, ar0, hR[ct]);
            hR[ct] = MFMA(zr1, ar1, hR[ct]);
            hR[ct] = MFMA(zin0, ai0, hR[ct]);
            hR[ct] = MFMA(zin1, ai1, hR[ct]);
            hI[ct] = MFMA(zr0, ai0, hI[ct]);
            hI[ct] = MFMA(zr1, ai1, hI[ct]);
            hI[ct] = MFMA(zi0, ar0, hI[ct]);
            hI[ct] = MFMA(zi1, ar1, hI[ct]);
        }

        // lambda: consume B-chain event l (E0 or B_{l-1}), hidden behind fwd GEMM
        if (l == 0) {
            consume(rootB, 0, 0, 1);
            lam = th[0] * sqrtf(red[0] * (1.0f / 48.0f));
        } else {
            consume(rootB, l, 2 * l, 6);          // B_{l-1}
            float sig2 = red[0] + 2.f * bre * red[1] + bre * bre * red[2]
                       + red[3] + 2.f * bim * red[4] + bim * bim * red[5];
            lam = th[l * 3] * sqrtf(sig2 * (1.0f / 48.0f));
        }

        // activation on registers; store Hn bf16 to LDS for bwd/final GEMM
        float cr = 0.f, ci = 0.f;
        #pragma unroll
        for (int ct = 0; ct < 8; ++ct) {
            const int t = ((wave & 3) * 8 + ct) * 16 + m;
            #pragma unroll
            for (int reg = 0; reg < 4; ++reg) {
                const int lr = rows16 + quad * 4 + reg;
                float Rr = hR[ct][reg], Ri = hI[ct][reg];
                float mr = fabsf(Rr), mi = fabsf(Ri);
                float fr = th1 * copysignf(fmaxf(mr - lam, 0.f), Rr);
                float fi = th1 * copysignf(fmaxf(mi - lam, 0.f), Ri);
                cr += (mr > lam) ? 1.f : 0.f;
                ci += (mi > lam) ? 1.f : 0.f;
                hR[ct][reg] = fr; hI[ct][reg] = fi;
                HreL[lr * HST + t] = f2bf(fr);
                HimL[lr * HST + t] = f2bf(fi);
            }
        }

        if (l == L_ - 1) { __syncthreads(); break; }   // publish Hn for final GEMM

        // reduce {cr,ci}; publish A_l (A-chain event l) before bwd GEMM
        #pragma unroll
        for (int o = 32; o > 0; o >>= 1) { cr += __shfl_xor(cr, o, 64); ci += __shfl_xor(ci, o, 64); }
        if (lane == 0) { red[16 + wave] = cr; red[24 + wave] = ci; }
        __syncthreads();                               // also publishes Hn LDS
        if (tid == 0) {
            float v2[2] = {0.f, 0.f};
            #pragma unroll
            for (int w = 0; w < NW; ++w) { v2[0] += red[16 + w]; v2[1] += red[24 + w]; }
            publishv(leafA, rootA, l, 2 * l + 1, v2, 2);
        }

        // backward GEMM: h = Hn @ A
        const ushort_t* Atlr = Atr + (size_t)l * 24576;
        const ushort_t* Atli = Ati + (size_t)l * 24576;
        f32x4 aR[3], aI[3];
        #pragma unroll
        for (int q = 0; q < 3; ++q) { aR[q] = (f32x4){0,0,0,0}; aI[q] = (f32x4){0,0,0,0}; }
        #pragma unroll
        for (int ks = 0; ks < 4; ++ks) {
            const int ksa = kq * 4 + ks;
            const int k0 = ksa * 32 + quad * 8;
            short8 hr = *(const short8*)&HreL[(rt * 16 + m) * HST + k0];
            short8 hi = *(const short8*)&HimL[(rt * 16 + m) * HST + k0];
            short8 hin = negbf(hi);
            #pragma unroll
            for (int ft = 0; ft < 3; ++ft) {
                short8 br = *(const short8*)(Atlr + (size_t)((ft * 16 + ksa) * 64 + lane) * 8);
                short8 bi = *(const short8*)(Atli + (size_t)((ft * 16 + ksa) * 64 + lane) * 8);
                aR[ft] = MFMA(hr, br, aR[ft]);
                aR[ft] = MFMA(hin, bi, aR[ft]);
                aI[ft] = MFMA(hr, bi, aI[ft]);
                aI[ft] = MFMA(hi, br, aI[ft]);
            }
        }
        #pragma unroll
        for (int ft = 0; ft < 3; ++ft) {
            #pragma unroll
            for (int reg = 0; reg < 4; ++reg) {
                pR[((wave * 3 + ft) * 16 + quad * 4 + reg) * 17 + m] = aR[ft][reg];
                pI[((wave * 3 + ft) * 16 + quad * 4 + reg) * 17 + m] = aI[ft][reg];
            }
        }
        __syncthreads();                               // publish pR/pI

        // quadratic partials (a = u - h from REGISTERS; z_old from LDS).
        // Needs NO scalar inputs -> publish B_l BEFORE consuming A_l, which
        // widens A_l's hiding window by this whole phase.
        float aRe[3], aIm[3], zR3[3], zI3[3];
        float S1 = 0.f, S2 = 0.f, S3 = 0.f, S4 = 0.f, S5 = 0.f, S6 = 0.f;
        #pragma unroll
        for (int k3 = 0; k3 < 3; ++k3) {
            int j = tid + k3 * THR;
            int r = j / 48, f = j - r * 48;
            int rt2 = r >> 4, lr = r & 15, ft = f >> 4, c = f & 15;
            float hRv = 0.f, hIv = 0.f;
            #pragma unroll
            for (int q = 0; q < 4; ++q) {
                hRv += pR[(((rt2 * 4 + q) * 3 + ft) * 16 + lr) * 17 + c];
                hIv += pI[(((rt2 * 4 + q) * 3 + ft) * 16 + lr) * 17 + c];
            }
            float zr = zreL[r * ZS + f], zi = zimL[r * ZS + f];
            float ar = uRe[k3] - hRv, ai = uIm[k3] - hIv;
            aRe[k3] = ar; aIm[k3] = ai; zR3[k3] = zr; zI3[k3] = zi;
            S1 += ar * ar; S2 += ar * zr; S3 += zr * zr;
            S4 += ai * ai; S5 += ai * zi; S6 += zi * zi;
        }

        // reduce S1..S6; publish B_l (B-chain event l+1)
        float v6[6] = {S1, S2, S3, S4, S5, S6};
        #pragma unroll
        for (int j = 0; j < 6; ++j) {
            #pragma unroll
            for (int o = 32; o > 0; o >>= 1) v6[j] += __shfl_xor(v6[j], o, 64);
        }
        if (lane == 0) {
            #pragma unroll
            for (int j = 0; j < 6; ++j) red[16 + wave * 6 + j] = v6[j];
        }
        __syncthreads();
        if (tid == 0) {
            float o6[6];
            #pragma unroll
            for (int j = 0; j < 6; ++j) {
                float s = 0.f;
                #pragma unroll
                for (int w = 0; w < NW; ++w) s += red[16 + w * 6 + j];
                o6[j] = s;
            }
            publishv(leafB, rootB, l + 1, 2 * l + 2, o6, 6);
        }

        // consume A_l (hidden behind bwd GEMM + partials + B publish) -> b
        consume(rootA, l, 2 * l + 1, 2);
        bre = th1 * red[0] * (1.0f / 48.0f);
        bim = th1 * red[1] * (1.0f / 48.0f);

        // z write from cached registers
        #pragma unroll
        for (int k3 = 0; k3 < 3; ++k3) {
            int j = tid + k3 * THR;
            int r = j / 48, f = j - r * 48;
            zreL[r * ZS + f] = aRe[k3] + bre * zR3[k3];
            zimL[r * ZS + f] = aIm[k3] + bim * zI3[k3];
        }
        __syncthreads();                 // z published for next fwd GEMM
    }

    // final: out = Hn(LDS) @ DFT
    f32x4 fR[3], fI[3];
    #pragma unroll
    for (int q = 0; q < 3; ++q) { fR[q] = (f32x4){0,0,0,0}; fI[q] = (f32x4){0,0,0,0}; }
    #pragma unroll
    for (int ks = 0; ks < 4; ++ks) {
        const int ksa = kq * 4 + ks;
        const int k0 = ksa * 32 + quad * 8;
        short8 hr = *(const short8*)&HreL[(rt * 16 + m) * HST + k0];
        short8 hi = *(const short8*)&HimL[(rt * 16 + m) * HST + k0];
        short8 hin = negbf(hi);
        #pragma unroll
        for (int ft = 0; ft < 3; ++ft) {
            short8 br = *(const short8*)(Dfr + (size_t)((ft * 16 + ksa) * 64 + lane) * 8);
            short8 bi = *(const short8*)(Dfi + (size_t)((ft * 16 + ksa) * 64 + lane) * 8);
            fR[ft] = MFMA(hr, br, fR[ft]);
            fR[ft] = MFMA(hin, bi, fR[ft]);
            fI[ft] = MFMA(hr, bi, fI[ft]);
            fI[ft] = MFMA(hi, br, fI[ft]);
        }
    }
    #pragma unroll
    for (int ft = 0; ft < 3; ++ft) {
        #pragma unroll
        for (int reg = 0; reg < 4; ++reg) {
            pR[((wave * 3 + ft) * 16 + quad * 4 + reg) * 17 + m] = fR[ft][reg];
            pI[((wave * 3 + ft) * 16 + quad * 4 + reg) * 17 + m] = fI[ft][reg];
        }
    }
    __syncthreads();
    float2* out2 = (float2*)out;
    #pragma unroll
    for (int k3 = 0; k3 < 3; ++k3) {
        int j = tid + k3 * THR;
        int r = j / 48, f = j - r * 48;
        int rt2 = r >> 4, lr = r & 15, ft = f >> 4, c = f & 15;
        float hRv = 0.f, hIv = 0.f;
        #pragma unroll
        for (int q = 0; q < 4; ++q) {
            hRv += pR[(((rt2 * 4 + q) * 3 + ft) * 16 + lr) * 17 + c];
            hIv += pI[(((rt2 * 4 + q) * 3 + ft) * 16 + lr) * 17 + c];
        }
        out2[(row0 + r) * 48 + f] = make_float2(hRv, hIv);
    }
}

extern "C" void kernel_launch(void* const* d_in, const int* in_sizes, int n_in,
                              void* d_out, int out_size, void* d_ws, size_t ws_size,
                              hipStream_t stream) {
    (void)in_sizes; (void)n_in; (void)out_size; (void)ws_size;
    const float* u  = (const float*)d_in[0];
    const float* Ar = (const float*)d_in[1];
    const float* Ai = (const float*)d_in[2];
    const float* th = (const float*)d_in[3];
    const float* Dr = (const float*)d_in[4];
    const float* Di = (const float*)d_in[5];
    float* out = (float*)d_out;

    char* p = (char*)d_ws;
    auto alloc = [&](size_t bytes) -> char* {
        char* r = p;
        p += (bytes + 255) & ~(size_t)255;
        return r;
    };
    uint_t*   syncbuf = (uint_t*)alloc((size_t)SYNC_DW * 4);
    ushort_t* Afr = (ushort_t*)alloc((size_t)L_ * 32768 * 2);
    ushort_t* Afi = (ushort_t*)alloc((size_t)L_ * 32768 * 2);
    ushort_t* Atr = (ushort_t*)alloc((size_t)L_ * 24576 * 2);
    ushort_t* Ati = (ushort_t*)alloc((size_t)L_ * 24576 * 2);
    ushort_t* Dfr = (ushort_t*)alloc((size_t)24576 * 2);
    ushort_t* Dfi = (ushort_t*)alloc((size_t)24576 * 2);

    k_pre<<<512, 256, 0, stream>>>(Ar, Ai, Dr, Di, Afr, Afi, Atr, Ati, Dfr, Dfi, syncbuf);

    const uint_t lds_bytes = 132608;
    hipFuncSetAttribute((const void*)k_lamp,
                        hipFuncAttributeMaxDynamicSharedMemorySize, (int)lds_bytes);
    // Regular (non-cooperative) launch: 256 blocks at 132.6 KB LDS = 1 block/CU
    // on 256 CUs -> all blocks co-resident by capacity; custom barrier is safe.
    k_lamp<<<dim3(NBLK), dim3(THR), lds_bytes, stream>>>(
        u, Afr, Afi, Atr, Ati, Dfr, Dfi, th, syncbuf, out);
}

// Round 11
// 291.409 us; speedup vs baseline: 1.0415x; 1.0415x over previous
//
#include <hip/hip_runtime.h>
#include <hip/hip_bf16.h>
#include <math.h>

#define B_   8192
#define F_   48
#define T_   512
#define L_   8
#define NBLK 256
#define THR  512
#define NW   8           // waves per block
#define RPB  32          // rows per block
#define HST  520         // H LDS row stride in shorts (1040B; 65 uint4)
#define ZS   52          // z LDS row stride in floats
#define LINE 32          // dwords per 128B line
#define NEVT 8           // E0 (sigma_0) + one merged event per layer l=0..6
// sync layout (dwords): cnt[1 line] | vals[NEVT][8 values x 1 line each]
#define VALS_OFF LINE
#define SYNC_DW  (LINE + NEVT * 8 * LINE)

typedef unsigned short ushort_t;
typedef unsigned int   uint_t;
typedef __attribute__((ext_vector_type(8))) short short8;
typedef __attribute__((ext_vector_type(4))) float f32x4;

#define MFMA(a,b,c) __builtin_amdgcn_mfma_f32_16x16x32_bf16(a,b,c,0,0,0)

__device__ inline ushort_t f2bf(float x) {
    __hip_bfloat16 h = __float2bfloat16(x);
    return *reinterpret_cast<ushort_t*>(&h);
}
__device__ inline short8 negbf(short8 v) {
    short8 r;
    #pragma unroll
    for (int i = 0; i < 8; ++i) r[i] = v[i] ^ (short)0x8000;
    return r;
}
__device__ inline short8 pack8(float4 a, float4 b) {
    short8 r;
    r[0]=(short)f2bf(a.x); r[1]=(short)f2bf(a.y); r[2]=(short)f2bf(a.z); r[3]=(short)f2bf(a.w);
    r[4]=(short)f2bf(b.x); r[5]=(short)f2bf(b.y); r[6]=(short)f2bf(b.z); r[7]=(short)f2bf(b.w);
    return r;
}

__device__ inline float aload(const float* p) {
    return __hip_atomic_load(p, __ATOMIC_RELAXED, __HIP_MEMORY_SCOPE_AGENT);
}
__device__ inline void afadd(float* p, float v) {
    (void)__hip_atomic_fetch_add(p, v, __ATOMIC_RELAXED, __HIP_MEMORY_SCOPE_AGENT);
}
__device__ inline void bar_add(uint_t* cnt) {
    (void)__hip_atomic_fetch_add(cnt, 1u, __ATOMIC_RELEASE, __HIP_MEMORY_SCOPE_AGENT);
}
__device__ inline void bar_wait(uint_t* cnt, uint_t tgt) {
    if (threadIdx.x == 0) {
        while (__hip_atomic_load(cnt, __ATOMIC_RELAXED, __HIP_MEMORY_SCOPE_AGENT) < tgt)
            __builtin_amdgcn_s_sleep(2);
        (void)__hip_atomic_load(cnt, __ATOMIC_ACQUIRE, __HIP_MEMORY_SCOPE_AGENT);
    }
    __syncthreads();
}

// ---------- prep: frag-linear bf16 layouts + zero sync region ----------
__global__ __launch_bounds__(256) void k_pre(
    const float* __restrict__ Ar, const float* __restrict__ Ai,
    const float* __restrict__ Dr, const float* __restrict__ Di,
    ushort_t* __restrict__ Afr, ushort_t* __restrict__ Afi,
    ushort_t* __restrict__ Atr, ushort_t* __restrict__ Ati,
    ushort_t* __restrict__ Dfr, ushort_t* __restrict__ Dfi,
    uint_t* __restrict__ syncbuf)
{
    const int gt = blockIdx.x * 256 + threadIdx.x;
    const int gs = gridDim.x * 256;
    if (gt < SYNC_DW) syncbuf[gt] = 0u;       // counter + afadd value slots
    for (int idx = gt; idx < L_ * 32768; idx += gs) {
        int j = idx & 7, rest = idx >> 3;
        int mm = rest & 15; rest >>= 4;
        int qq = rest & 3;  rest >>= 2;
        int k2 = rest & 1;  rest >>= 1;
        int tile = rest & 31;
        int l = rest >> 5;
        int t = tile * 16 + mm, k = k2 * 32 + qq * 8 + j;
        float vr = 0.f, vi = 0.f;
        if (k < 48) { int g = l * 24576 + t * 48 + k; vr = Ar[g]; vi = Ai[g]; }
        Afr[idx] = f2bf(vr); Afi[idx] = f2bf(vi);
    }
    for (int idx = gt; idx < L_ * 24576; idx += gs) {
        int j = idx & 7, rest = idx >> 3;
        int mm = rest & 15; rest >>= 4;
        int qq = rest & 3;  rest >>= 2;
        int ks = rest & 15; rest >>= 4;
        int ft = rest % 3;
        int l = rest / 3;
        int f = ft * 16 + mm, k = ks * 32 + qq * 8 + j;
        int g = l * 24576 + k * 48 + f;
        Atr[idx] = f2bf(Ar[g]); Ati[idx] = f2bf(Ai[g]);
    }
    for (int idx = gt; idx < 24576; idx += gs) {
        int j = idx & 7, rest = idx >> 3;
        int mm = rest & 15; rest >>= 4;
        int qq = rest & 3;  rest >>= 2;
        int ks = rest & 15;
        int ft = rest >> 4;
        int f = ft * 16 + mm, k = ks * 32 + qq * 8 + j;
        Dfr[idx] = f2bf(Dr[k * 48 + f]); Dfi[idx] = f2bf(Di[k * 48 + f]);
    }
}

// ---------- persistent cooperative kernel ----------
// 8 global sync events, R1 transport (publisher-side afadd aggregation,
// single cumulative counter, all-thread broadcast reads):
//   E0:     sigma_0 = sum||u||^2 (1 value line), consumed after fwd GEMM 0.
//   E_{l+1} (l=0..6): {cr, ci, S1..S6} on 8 SEPARATE lines (8 parallel
//     256-deep RMW chains), published after the quadratic-partials phase,
//     consumed immediately (exposed ~1 chain); every block then derives
//     b_l AND sigma_{l+1} locally:
//       bre = th1*CR/48, bim = th1*CI/48
//       sigma^2 = S1 + 2 bre S2 + bre^2 S3 + S4 + 2 bim S5 + bim^2 S6
__global__ __launch_bounds__(THR, 2) void k_lamp(
    const float* __restrict__ u,
    const ushort_t* __restrict__ Afr, const ushort_t* __restrict__ Afi,
    const ushort_t* __restrict__ Atr, const ushort_t* __restrict__ Ati,
    const ushort_t* __restrict__ Dfr, const ushort_t* __restrict__ Dfi,
    const float* __restrict__ th,
    uint_t* syncbuf,
    float* __restrict__ out)
{
    extern __shared__ char dyn[];
    float*    pR   = (float*)dyn;                  // [8][3][16][17] 26112 B
    float*    pI   = pR + 8 * 3 * 16 * 17;         // 26112 B
    float*    zreL = pI + 8 * 3 * 16 * 17;         // 6656 B
    float*    zimL = zreL + RPB * ZS;              // 6656 B
    float*    red  = zimL + RPB * ZS;              // 512 B (128 floats)
    ushort_t* HreL = (ushort_t*)(red + 128);       // 33280 B
    ushort_t* HimL = HreL + RPB * HST;             // 33280 B  => 132608 B

    uint_t* cnt  = syncbuf;                        // counter line
    float*  vals = (float*)syncbuf + VALS_OFF;     // event e, value j at
    auto vslot = [&](int e, int j) { return vals + (size_t)(e * 8 + j) * LINE; };

    const int tid = threadIdx.x, blk = blockIdx.x;
    const int row0 = blk * RPB;
    const int wave = tid >> 6, lane = tid & 63;
    const int quad = lane >> 4, m = lane & 15;
    const int rows16 = (wave >> 2) * 16;           // fwd: which 16-row tile
    const int rt = wave >> 2, kq = wave & 3;       // bwd: row-tile / K-quarter
    const float2* u2 = (const float2*)u;
    uint_t tgt = 0;

    // persistent H fragments (f32)
    f32x4 hR[8], hI[8];
    #pragma unroll
    for (int ct = 0; ct < 8; ++ct) { hR[ct] = (f32x4){0,0,0,0}; hI[ct] = (f32x4){0,0,0,0}; }

    // prologue: u -> regs + z LDS; ||u||^2 partial -> E0 (afadd aggregate)
    float uRe[3], uIm[3];
    float acc = 0.f;
    #pragma unroll
    for (int k3 = 0; k3 < 3; ++k3) {
        int j = tid + k3 * THR;
        int r = j / 48, c = j - r * 48;
        float2 v = u2[(row0 + r) * 48 + c];
        uRe[k3] = v.x; uIm[k3] = v.y;
        zreL[r * ZS + c] = v.x; zimL[r * ZS + c] = v.y;
        acc += v.x * v.x + v.y * v.y;
    }
    #pragma unroll
    for (int o = 32; o > 0; o >>= 1) acc += __shfl_xor(acc, o, 64);
    __syncthreads();                         // publishes z LDS
    if (lane == 0) red[16 + wave] = acc;
    __syncthreads();
    if (tid == 0) {
        float t = 0.f;
        #pragma unroll
        for (int w = 0; w < NW; ++w) t += red[16 + w];
        afadd(vslot(0, 0), t); bar_add(cnt);
    }
    tgt += NBLK;

    float lam = 0.f;
    for (int l = 0; l < L_; ++l) {
        const float th1 = th[l * 3 + 1];

        // z A-frags from LDS fp32 (K=48 padded to 64)
        const float* zpr = zreL + (rows16 + m) * ZS;
        const float* zpi = zimL + (rows16 + m) * ZS;
        short8 zr0 = pack8(*(const float4*)(zpr + quad * 8), *(const float4*)(zpr + quad * 8 + 4));
        short8 zi0 = pack8(*(const float4*)(zpi + quad * 8), *(const float4*)(zpi + quad * 8 + 4));
        short8 zr1 = {0,0,0,0,0,0,0,0}, zi1 = {0,0,0,0,0,0,0,0};
        if (quad < 2) {
            zr1 = pack8(*(const float4*)(zpr + 32 + quad * 8), *(const float4*)(zpr + 36 + quad * 8));
            zi1 = pack8(*(const float4*)(zpi + 32 + quad * 8), *(const float4*)(zpi + 36 + quad * 8));
        }
        short8 zin0 = negbf(zi0), zin1 = negbf(zi1);

        // forward GEMM accumulating straight onto H_old
        const ushort_t* Aflr = Afr + (size_t)l * 32768;
        const ushort_t* Afli = Afi + (size_t)l * 32768;
        #pragma unroll
        for (int ct = 0; ct < 8; ++ct) {
            const int tile = (wave & 3) * 8 + ct;
            const ushort_t* rp = Aflr + (size_t)(tile * 2) * 512 + lane * 8;
            const ushort_t* ip = Afli + (size_t)(tile * 2) * 512 + lane * 8;
            short8 ar0 = *(const short8*)rp;
            short8 ar1 = *(const short8*)(rp + 512);
            short8 ai0 = *(const short8*)ip;
            short8 ai1 = *(const short8*)(ip + 512);
            hR[ct] = MFMA(zr0, ar0, hR[ct]);
            hR[ct] = MFMA(zr1, ar1, hR[ct]);
            hR[ct] = MFMA(zin0, ai0, hR[ct]);
            hR[ct] = MFMA(zin1, ai1, hR[ct]);
            hI[ct] = MFMA(zr0, ai0, hI[ct]);
            hI[ct] = MFMA(zr1, ai1, hI[ct]);
            hI[ct] = MFMA(zi0, ar0, hI[ct]);
            hI[ct] = MFMA(zi1, ar1, hI[ct]);
        }

        // E0 wait hides behind fwd GEMM 0; later layers have lam already.
        if (l == 0) {
            bar_wait(cnt, tgt);
            lam = th[0] * sqrtf(aload(vslot(0, 0)) * (1.0f / 48.0f));
        }

        // activation on registers; store Hn bf16 to LDS for bwd/final GEMM
        float cr = 0.f, ci = 0.f;
        #pragma unroll
        for (int ct = 0; ct < 8; ++ct) {
            const int t = ((wave & 3) * 8 + ct) * 16 + m;
            #pragma unroll
            for (int reg = 0; reg < 4; ++reg) {
                const int lr = rows16 + quad * 4 + reg;
                float Rr = hR[ct][reg], Ri = hI[ct][reg];
                float mr = fabsf(Rr), mi = fabsf(Ri);
                float fr = th1 * copysignf(fmaxf(mr - lam, 0.f), Rr);
                float fi = th1 * copysignf(fmaxf(mi - lam, 0.f), Ri);
                cr += (mr > lam) ? 1.f : 0.f;
                ci += (mi > lam) ? 1.f : 0.f;
                hR[ct][reg] = fr; hI[ct][reg] = fi;
                HreL[lr * HST + t] = f2bf(fr);
                HimL[lr * HST + t] = f2bf(fi);
            }
        }

        if (l == L_ - 1) { __syncthreads(); break; }   // publish Hn for final GEMM
        __syncthreads();                               // publish Hn for bwd GEMM

        // backward GEMM: h = Hn @ A
        const ushort_t* Atlr = Atr + (size_t)l * 24576;
        const ushort_t* Atli = Ati + (size_t)l * 24576;
        f32x4 aR[3], aI[3];
        #pragma unroll
        for (int q = 0; q < 3; ++q) { aR[q] = (f32x4){0,0,0,0}; aI[q] = (f32x4){0,0,0,0}; }
        #pragma unroll
        for (int ks = 0; ks < 4; ++ks) {
            const int ksa = kq * 4 + ks;
            const int k0 = ksa * 32 + quad * 8;
            short8 hr = *(const short8*)&HreL[(rt * 16 + m) * HST + k0];
            short8 hi = *(const short8*)&HimL[(rt * 16 + m) * HST + k0];
            short8 hin = negbf(hi);
            #pragma unroll
            for (int ft = 0; ft < 3; ++ft) {
                short8 br = *(const short8*)(Atlr + (size_t)((ft * 16 + ksa) * 64 + lane) * 8);
                short8 bi = *(const short8*)(Atli + (size_t)((ft * 16 + ksa) * 64 + lane) * 8);
                aR[ft] = MFMA(hr, br, aR[ft]);
                aR[ft] = MFMA(hin, bi, aR[ft]);
                aI[ft] = MFMA(hr, bi, aI[ft]);
                aI[ft] = MFMA(hi, br, aI[ft]);
            }
        }
        #pragma unroll
        for (int ft = 0; ft < 3; ++ft) {
            #pragma unroll
            for (int reg = 0; reg < 4; ++reg) {
                pR[((wave * 3 + ft) * 16 + quad * 4 + reg) * 17 + m] = aR[ft][reg];
                pI[((wave * 3 + ft) * 16 + quad * 4 + reg) * 17 + m] = aI[ft][reg];
            }
        }
        __syncthreads();                               // publish pR/pI

        // quadratic partials (a = u - h from regs; z_old from LDS, cached)
        float aRe[3], aIm[3], zR3[3], zI3[3];
        float S1 = 0.f, S2 = 0.f, S3 = 0.f, S4 = 0.f, S5 = 0.f, S6 = 0.f;
        #pragma unroll
        for (int k3 = 0; k3 < 3; ++k3) {
            int j = tid + k3 * THR;
            int r = j / 48, f = j - r * 48;
            int rt2 = r >> 4, lr = r & 15, ft = f >> 4, c = f & 15;
            float hRv = 0.f, hIv = 0.f;
            #pragma unroll
            for (int q = 0; q < 4; ++q) {
                hRv += pR[(((rt2 * 4 + q) * 3 + ft) * 16 + lr) * 17 + c];
                hIv += pI[(((rt2 * 4 + q) * 3 + ft) * 16 + lr) * 17 + c];
            }
            float zr = zreL[r * ZS + f], zi = zimL[r * ZS + f];
            float ar = uRe[k3] - hRv, ai = uIm[k3] - hIv;
            aRe[k3] = ar; aIm[k3] = ai; zR3[k3] = zr; zI3[k3] = zi;
            S1 += ar * ar; S2 += ar * zr; S3 += zr * zr;
            S4 += ai * ai; S5 += ai * zi; S6 += zi * zi;
        }

        // block-reduce 8 values; tid0 afadds each to its OWN line (8 parallel
        // 256-deep chains) + one counter bump; then the exposed wait.
        float v8[8] = {cr, ci, S1, S2, S3, S4, S5, S6};
        #pragma unroll
        for (int j = 0; j < 8; ++j) {
            #pragma unroll
            for (int o = 32; o > 0; o >>= 1) v8[j] += __shfl_xor(v8[j], o, 64);
        }
        if (lane == 0) {
            #pragma unroll
            for (int j = 0; j < 8; ++j) red[16 + wave * 8 + j] = v8[j];
        }
        __syncthreads();
        if (tid == 0) {
            #pragma unroll
            for (int j = 0; j < 8; ++j) {
                float s = 0.f;
                #pragma unroll
                for (int w = 0; w < NW; ++w) s += red[16 + w * 8 + j];
                afadd(vslot(l + 1, j), s);
            }
            bar_add(cnt);
        }
        tgt += NBLK;
        bar_wait(cnt, tgt);

        // every thread reads the aggregated values directly (broadcast loads)
        const float CR = aload(vslot(l + 1, 0));
        const float CI = aload(vslot(l + 1, 1));
        const float G1 = aload(vslot(l + 1, 2));
        const float G2 = aload(vslot(l + 1, 3));
        const float G3 = aload(vslot(l + 1, 4));
        const float G4 = aload(vslot(l + 1, 5));
        const float G5 = aload(vslot(l + 1, 6));
        const float G6 = aload(vslot(l + 1, 7));
        const float bre = th1 * CR * (1.0f / 48.0f);
        const float bim = th1 * CI * (1.0f / 48.0f);
        const float sig2 = G1 + 2.f * bre * G2 + bre * bre * G3
                         + G4 + 2.f * bim * G5 + bim * bim * G6;
        lam = th[(l + 1) * 3] * sqrtf(sig2 * (1.0f / 48.0f));

        // z write from cached registers
        #pragma unroll
        for (int k3 = 0; k3 < 3; ++k3) {
            int j = tid + k3 * THR;
            int r = j / 48, f = j - r * 48;
            zreL[r * ZS + f] = aRe[k3] + bre * zR3[k3];
            zimL[r * ZS + f] = aIm[k3] + bim * zI3[k3];
        }
        __syncthreads();                 // z published for next fwd GEMM
    }

    // final: out = Hn(LDS) @ DFT
    f32x4 fR[3], fI[3];
    #pragma unroll
    for (int q = 0; q < 3; ++q) { fR[q] = (f32x4){0,0,0,0}; fI[q] = (f32x4){0,0,0,0}; }
    #pragma unroll
    for (int ks = 0; ks < 4; ++ks) {
        const int ksa = kq * 4 + ks;
        const int k0 = ksa * 32 + quad * 8;
        short8 hr = *(const short8*)&HreL[(rt * 16 + m) * HST + k0];
        short8 hi = *(const short8*)&HimL[(rt * 16 + m) * HST + k0];
        short8 hin = negbf(hi);
        #pragma unroll
        for (int ft = 0; ft < 3; ++ft) {
            short8 br = *(const short8*)(Dfr + (size_t)((ft * 16 + ksa) * 64 + lane) * 8);
            short8 bi = *(const short8*)(Dfi + (size_t)((ft * 16 + ksa) * 64 + lane) * 8);
            fR[ft] = MFMA(hr, br, fR[ft]);
            fR[ft] = MFMA(hin, bi, fR[ft]);
            fI[ft] = MFMA(hr, bi, fI[ft]);
            fI[ft] = MFMA(hi, br, fI[ft]);
        }
    }
    #pragma unroll
    for (int ft = 0; ft < 3; ++ft) {
        #pragma unroll
        for (int reg = 0; reg < 4; ++reg) {
            pR[((wave * 3 + ft) * 16 + quad * 4 + reg) * 17 + m] = fR[ft][reg];
            pI[((wave * 3 + ft) * 16 + quad * 4 + reg) * 17 + m] = fI[ft][reg];
        }
    }
    __syncthreads();
    float2* out2 = (float2*)out;
    #pragma unroll
    for (int k3 = 0; k3 < 3; ++k3) {
        int j = tid + k3 * THR;
        int r = j / 48, f = j - r * 48;
        int rt2 = r >> 4, lr = r & 15, ft = f >> 4, c = f & 15;
        float hRv = 0.f, hIv = 0.f;
        #pragma unroll
        for (int q = 0; q < 4; ++q) {
            hRv += pR[(((rt2 * 4 + q) * 3 + ft) * 16 + lr) * 17 + c];
            hIv += pI[(((rt2 * 4 + q) * 3 + ft) * 16 + lr) * 17 + c];
        }
        out2[(row0 + r) * 48 + f] = make_float2(hRv, hIv);
    }
}

extern "C" void kernel_launch(void* const* d_in, const int* in_sizes, int n_in,
                              void* d_out, int out_size, void* d_ws, size_t ws_size,
                              hipStream_t stream) {
    (void)in_sizes; (void)n_in; (void)out_size; (void)ws_size;
    const float* u  = (const float*)d_in[0];
    const float* Ar = (const float*)d_in[1];
    const float* Ai = (const float*)d_in[2];
    const float* th = (const float*)d_in[3];
    const float* Dr = (const float*)d_in[4];
    const float* Di = (const float*)d_in[5];
    float* out = (float*)d_out;

    char* p = (char*)d_ws;
    auto alloc = [&](size_t bytes) -> char* {
        char* r = p;
        p += (bytes + 255) & ~(size_t)255;
        return r;
    };
    uint_t*   syncbuf = (uint_t*)alloc((size_t)SYNC_DW * 4);
    ushort_t* Afr = (ushort_t*)alloc((size_t)L_ * 32768 * 2);
    ushort_t* Afi = (ushort_t*)alloc((size_t)L_ * 32768 * 2);
    ushort_t* Atr = (ushort_t*)alloc((size_t)L_ * 24576 * 2);
    ushort_t* Ati = (ushort_t*)alloc((size_t)L_ * 24576 * 2);
    ushort_t* Dfr = (ushort_t*)alloc((size_t)24576 * 2);
    ushort_t* Dfi = (ushort_t*)alloc((size_t)24576 * 2);

    k_pre<<<1024, 256, 0, stream>>>(Ar, Ai, Dr, Di, Afr, Afi, Atr, Ati, Dfr, Dfi, syncbuf);

    const uint_t lds_bytes = 132608;
    hipFuncSetAttribute((const void*)k_lamp,
                        hipFuncAttributeMaxDynamicSharedMemorySize, (int)lds_bytes);
    void* args[] = { (void*)&u, (void*)&Afr, (void*)&Afi, (void*)&Atr, (void*)&Ati,
                     (void*)&Dfr, (void*)&Dfi, (void*)&th,
                     (void*)&syncbuf, (void*)&out };
    hipLaunchCooperativeKernel((void*)k_lamp, dim3(NBLK), dim3(THR), args,
                               lds_bytes, stream);
}